// Round 9
// baseline (276.450 us; speedup 1.0000x reference)
//
#include <hip/hip_runtime.h>
#include <math.h>

#define N_NODES  20000
#define N_EDGES  320000
#define N_GRAPHS 200
#define MAXN     100
#define F_IN     128
#define F_H      256
#define F_L      64
#define P_PAIRS  4950
#define P_PAD    4992                       // P_PAIRS padded to multiple of 64
#define ADJ_SIZE (N_GRAPHS * MAXN * MAXN)   // 2,000,000
#define MU_OFF   ADJ_SIZE
#define LV_OFF   (ADJ_SIZE + N_GRAPHS * F_L)

#define SCAN_NB  ((N_NODES + 255) / 256)    // 79 blocks

static inline int ceil_div(int a, int b) { return (a + b - 1) / b; }

typedef __attribute__((ext_vector_type(8))) short bf16x8;   // 4 VGPRs
typedef __attribute__((ext_vector_type(4))) float f32x4;    // MFMA acc

// fp32 -> bf16 round-to-nearest-even
static __device__ inline unsigned short f2bf(float f) {
    union { float f; unsigned u; } v; v.f = f;
    unsigned r = (v.u + 0x7FFFu + ((v.u >> 16) & 1u)) >> 16;
    return (unsigned short)r;
}
static __device__ inline float bf2f(unsigned short s) {
    union { unsigned u; float f; } v; v.u = (unsigned)s << 16; return v.f;
}
static __device__ inline float4 ubf4(ushort4 u) {
    float4 f;
    f.x = bf2f(u.x); f.y = bf2f(u.y); f.z = bf2f(u.z); f.w = bf2f(u.w);
    return f;
}

// ---------------------------------------------------------------- degree histogram (int)
__global__ __launch_bounds__(256) void k_deg(const int* __restrict__ dst,
                                             int* __restrict__ deg, int nE) {
    int i = blockIdx.x * blockDim.x + threadIdx.x;
    if (i < nE) atomicAdd(deg + dst[i], 1);
}

// ---------------------------------------------------------------- 2-phase parallel scan (+dinv fused)
__global__ __launch_bounds__(256) void k_scan_local(const int* __restrict__ deg,
                                                    int* __restrict__ rowptr,
                                                    int* __restrict__ bsum,
                                                    float* __restrict__ dinv, int n) {
    __shared__ int tmp[256];
    int i = blockIdx.x * 256 + threadIdx.x;
    int v = (i < n) ? deg[i] : 0;
    if (i < n) dinv[i] = rsqrtf((float)v + 1.0f);   // +1 self-loop
    tmp[threadIdx.x] = v;
    __syncthreads();
    #pragma unroll
    for (int off = 1; off < 256; off <<= 1) {
        int t = (threadIdx.x >= (unsigned)off) ? tmp[threadIdx.x - off] : 0;
        __syncthreads();
        tmp[threadIdx.x] += t;
        __syncthreads();
    }
    if (i < n) rowptr[i + 1] = tmp[threadIdx.x];
    if (threadIdx.x == 255) bsum[blockIdx.x] = tmp[255];
}

// Phase B (merged): each block reduces bsum[0..blockIdx) then adds the offset
__global__ __launch_bounds__(256) void k_scan_add(int* __restrict__ rowptr,
                                                  const int* __restrict__ bsum, int n) {
    __shared__ int red[256];
    int t = threadIdx.x;
    red[t] = (t < (int)blockIdx.x) ? bsum[t] : 0;   // SCAN_NB (79) < 256
    __syncthreads();
    #pragma unroll
    for (int off = 128; off > 0; off >>= 1) {
        if (t < off) red[t] += red[t + off];
        __syncthreads();
    }
    int offv = red[0];
    int i = blockIdx.x * 256 + t;
    if (i < n) rowptr[i + 1] += offv;
    if (blockIdx.x == 0 && t == 0) rowptr[0] = 0;
}

// ---------------------------------------------------------------- CSR fill
__global__ __launch_bounds__(256) void k_fill(const int* __restrict__ src,
                                              const int* __restrict__ dst,
                                              const int* __restrict__ rowptr,
                                              int* __restrict__ fill,
                                              int* __restrict__ col, int nE) {
    int e = blockIdx.x * blockDim.x + threadIdx.x;
    if (e >= nE) return;
    int d = dst[e];
    int pos = rowptr[d] + atomicAdd(fill + d, 1);
    col[pos] = src[e];
}

// ---------------------------------------------------------------- fused xs-cast + weight prepack
// Segment 0: xs[v][f] = bf16(dinv[v]*x[v][f]) (float4 granular).
// Then prepack W1, W2, D3 into B-fragment order:
//   Bp[((kt*NT+nt)*64+lane)*8+j] = bf16(W[kt*32+(lane>>4)*8+j][nt*16+(lane&15)])
#define CV_END 640000                      // N_NODES*F_IN/4
#define PP_S1  32768                       // W1: 128*256
#define PP_S2  98304                       // + W2: 256*256
#define PP_END 1376256                     // + D3: 256*4992
__global__ __launch_bounds__(256) void k_cvt_prepack(
        const float* __restrict__ x, const float* __restrict__ dinv,
        unsigned short* __restrict__ xs,
        const float* __restrict__ W1, const float* __restrict__ W2,
        const float* __restrict__ D3,
        unsigned short* __restrict__ W1p, unsigned short* __restrict__ W2p,
        unsigned short* __restrict__ D3p) {
    int tid = blockIdx.x * 256 + threadIdx.x;
    if (tid < CV_END) {
        int v = tid >> 5;                  // 32 float4 per row of 128
        float dv = dinv[v];
        float4 val = ((const float4*)x)[tid];
        ushort4 o;
        o.x = f2bf(val.x * dv); o.y = f2bf(val.y * dv);
        o.z = f2bf(val.z * dv); o.w = f2bf(val.w * dv);
        ((ushort4*)xs)[tid] = o;
        return;
    }
    int pid = tid - CV_END;
    const float* W; unsigned short* Bp; int N, NP, t;
    if (pid < PP_S1)      { t = pid;          W = W1; Bp = W1p; N = 256;     NP = 256; }
    else if (pid < PP_S2) { t = pid - PP_S1;  W = W2; Bp = W2p; N = 256;     NP = 256; }
    else if (pid < PP_END){ t = pid - PP_S2;  W = D3; Bp = D3p; N = P_PAIRS; NP = P_PAD; }
    else return;
    int j    = t & 7;
    int lane = (t >> 3) & 63;
    int tile = t >> 9;
    int NT = NP >> 4;
    int nt = tile % NT;
    int kt = tile / NT;
    int k = kt * 32 + (lane >> 4) * 8 + j;
    int n = nt * 16 + (lane & 15);
    Bp[t] = (n < N) ? f2bf(W[(size_t)k * N + n]) : (unsigned short)0;
}

// ---------------------------------------------------------------- unified MFMA bf16 GEMM
// Y = epi(A[M,K]bf16 @ Bp + bias); LDS-free, barrier-free; wave tile 32x64, block 128x64.
// MODE 1: relu -> bf16           (layer-2: h2)
// MODE 2: relu * dinv[m] -> bf16 (layer-1: h1s, pre-scaled for gather)
// MODE 3: sigmoid -> fp32        (decoder D3)
template<int KDIM, int MODE>
__global__ __launch_bounds__(256) void k_gemm(const unsigned short* __restrict__ A,
                                              const unsigned short* __restrict__ Bp,
                                              void* __restrict__ Y,
                                              const float* __restrict__ bias,
                                              const float* __restrict__ dinv,
                                              int M, int N, int NP) {
    constexpr int KT = KDIM / 32;
    const int NT   = NP >> 4;
    const int lane = threadIdx.x & 63;
    const int wave = threadIdx.x >> 6;
    const int bm   = blockIdx.y * 128 + wave * 32;
    const int ng0  = blockIdx.x * 4;
    const int quad = lane >> 4;
    const int l15  = lane & 15;

    int m0 = bm + l15;
    int m1 = m0 + 16;
    int m0c = min(m0, M - 1), m1c = min(m1, M - 1);

    f32x4 acc[2][4];
    #pragma unroll
    for (int i = 0; i < 2; ++i)
        #pragma unroll
        for (int nt = 0; nt < 4; ++nt) acc[i][nt] = (f32x4){0.f, 0.f, 0.f, 0.f};

    #pragma unroll
    for (int kt = 0; kt < KT; ++kt) {
        bf16x8 a0 = *(const bf16x8*)(A + (size_t)m0c * KDIM + kt * 32 + quad * 8);
        bf16x8 a1 = *(const bf16x8*)(A + (size_t)m1c * KDIM + kt * 32 + quad * 8);
        #pragma unroll
        for (int nt = 0; nt < 4; ++nt) {
            bf16x8 b = *(const bf16x8*)(Bp + (((size_t)kt * NT + ng0 + nt) * 64 + lane) * 8);
            acc[0][nt] = __builtin_amdgcn_mfma_f32_16x16x32_bf16(a0, b, acc[0][nt], 0, 0, 0);
            acc[1][nt] = __builtin_amdgcn_mfma_f32_16x16x32_bf16(a1, b, acc[1][nt], 0, 0, 0);
        }
    }

    // C/D layout: col = lane&15, row = quad*4 + reg
    #pragma unroll
    for (int i = 0; i < 2; ++i) {
        #pragma unroll
        for (int r = 0; r < 4; ++r) {
            int gm = bm + i * 16 + quad * 4 + r;
            if (gm >= M) continue;
            float dv = (MODE == 2) ? dinv[gm] : 1.0f;
            #pragma unroll
            for (int nt = 0; nt < 4; ++nt) {
                int gn = ((ng0 + nt) << 4) + l15;
                if (gn >= N) continue;
                float s = acc[i][nt][r] + bias[gn];
                if constexpr (MODE == 1) {
                    ((unsigned short*)Y)[(size_t)gm * N + gn] = f2bf(fmaxf(s, 0.0f));
                } else if constexpr (MODE == 2) {
                    ((unsigned short*)Y)[(size_t)gm * N + gn] = f2bf(fmaxf(s, 0.0f) * dv);
                } else {
                    ((float*)Y)[(size_t)gm * N + gn] = 1.0f / (1.0f + expf(-s));
                }
            }
        }
    }
}

// ---------------------------------------------------------------- gather layer 1 (128 feats)
__global__ __launch_bounds__(256) void k_gather1(const unsigned short* __restrict__ xs,
                                                 const int* __restrict__ rowptr,
                                                 const int* __restrict__ col,
                                                 const float* __restrict__ dinv,
                                                 unsigned short* __restrict__ outp) {
    int v = blockIdx.x * 4 + (threadIdx.x >> 6);
    if (v >= N_NODES) return;
    int lane = threadIdx.x & 63;
    int beg = rowptr[v], end = rowptr[v + 1];
    float2 a0 = make_float2(0.f, 0.f), a1 = make_float2(0.f, 0.f);
    float2 a2 = make_float2(0.f, 0.f), a3 = make_float2(0.f, 0.f);
    int i = beg;
    for (; i + 8 <= end; i += 8) {
        int s0 = col[i + 0], s1 = col[i + 1], s2 = col[i + 2], s3 = col[i + 3];
        int s4 = col[i + 4], s5 = col[i + 5], s6 = col[i + 6], s7 = col[i + 7];
        ushort2 u0 = ((const ushort2*)(xs + (size_t)s0 * F_IN))[lane];
        ushort2 u1 = ((const ushort2*)(xs + (size_t)s1 * F_IN))[lane];
        ushort2 u2 = ((const ushort2*)(xs + (size_t)s2 * F_IN))[lane];
        ushort2 u3 = ((const ushort2*)(xs + (size_t)s3 * F_IN))[lane];
        ushort2 u4 = ((const ushort2*)(xs + (size_t)s4 * F_IN))[lane];
        ushort2 u5 = ((const ushort2*)(xs + (size_t)s5 * F_IN))[lane];
        ushort2 u6 = ((const ushort2*)(xs + (size_t)s6 * F_IN))[lane];
        ushort2 u7 = ((const ushort2*)(xs + (size_t)s7 * F_IN))[lane];
        a0.x += bf2f(u0.x) + bf2f(u4.x); a0.y += bf2f(u0.y) + bf2f(u4.y);
        a1.x += bf2f(u1.x) + bf2f(u5.x); a1.y += bf2f(u1.y) + bf2f(u5.y);
        a2.x += bf2f(u2.x) + bf2f(u6.x); a2.y += bf2f(u2.y) + bf2f(u6.y);
        a3.x += bf2f(u3.x) + bf2f(u7.x); a3.y += bf2f(u3.y) + bf2f(u7.y);
    }
    for (; i < end; ++i) {
        int s = col[i];
        ushort2 u = ((const ushort2*)(xs + (size_t)s * F_IN))[lane];
        a0.x += bf2f(u.x); a0.y += bf2f(u.y);
    }
    float dv = dinv[v];
    ushort2 uv = ((const ushort2*)(xs + (size_t)v * F_IN))[lane];
    float ox = dv * (a0.x + a1.x + a2.x + a3.x + bf2f(uv.x));
    float oy = dv * (a0.y + a1.y + a2.y + a3.y + bf2f(uv.y));
    ushort2 ob; ob.x = f2bf(ox); ob.y = f2bf(oy);
    ((ushort2*)outp)[(size_t)v * 64 + lane] = ob;
}

// ---------------------------------------------------------------- gather layer 2 (256 feats)
__global__ __launch_bounds__(256) void k_gather2(const unsigned short* __restrict__ Hs,
                                                 const int* __restrict__ rowptr,
                                                 const int* __restrict__ col,
                                                 const float* __restrict__ dinv,
                                                 unsigned short* __restrict__ outp) {
    int v = blockIdx.x * 4 + (threadIdx.x >> 6);
    if (v >= N_NODES) return;
    int lane = threadIdx.x & 63;
    int beg = rowptr[v], end = rowptr[v + 1];
    float4 a0 = make_float4(0.f, 0.f, 0.f, 0.f);
    float4 a1 = make_float4(0.f, 0.f, 0.f, 0.f);
    float4 a2 = make_float4(0.f, 0.f, 0.f, 0.f);
    float4 a3 = make_float4(0.f, 0.f, 0.f, 0.f);
    int i = beg;
    for (; i + 8 <= end; i += 8) {
        int s0 = col[i + 0], s1 = col[i + 1], s2 = col[i + 2], s3 = col[i + 3];
        int s4 = col[i + 4], s5 = col[i + 5], s6 = col[i + 6], s7 = col[i + 7];
        float4 h0 = ubf4(((const ushort4*)(Hs + (size_t)s0 * F_H))[lane]);
        float4 h1 = ubf4(((const ushort4*)(Hs + (size_t)s1 * F_H))[lane]);
        float4 h2 = ubf4(((const ushort4*)(Hs + (size_t)s2 * F_H))[lane]);
        float4 h3 = ubf4(((const ushort4*)(Hs + (size_t)s3 * F_H))[lane]);
        float4 h4 = ubf4(((const ushort4*)(Hs + (size_t)s4 * F_H))[lane]);
        float4 h5 = ubf4(((const ushort4*)(Hs + (size_t)s5 * F_H))[lane]);
        float4 h6 = ubf4(((const ushort4*)(Hs + (size_t)s6 * F_H))[lane]);
        float4 h7 = ubf4(((const ushort4*)(Hs + (size_t)s7 * F_H))[lane]);
        a0.x += h0.x + h4.x; a0.y += h0.y + h4.y; a0.z += h0.z + h4.z; a0.w += h0.w + h4.w;
        a1.x += h1.x + h5.x; a1.y += h1.y + h5.y; a1.z += h1.z + h5.z; a1.w += h1.w + h5.w;
        a2.x += h2.x + h6.x; a2.y += h2.y + h6.y; a2.z += h2.z + h6.z; a2.w += h2.w + h6.w;
        a3.x += h3.x + h7.x; a3.y += h3.y + h7.y; a3.z += h3.z + h7.z; a3.w += h3.w + h7.w;
    }
    for (; i < end; ++i) {
        int s = col[i];
        float4 h = ubf4(((const ushort4*)(Hs + (size_t)s * F_H))[lane]);
        a0.x += h.x; a0.y += h.y; a0.z += h.z; a0.w += h.w;
    }
    float dv = dinv[v];
    float4 hv = ubf4(((const ushort4*)(Hs + (size_t)v * F_H))[lane]);
    float ox = dv * (a0.x + a1.x + a2.x + a3.x + hv.x);
    float oy = dv * (a0.y + a1.y + a2.y + a3.y + hv.y);
    float oz = dv * (a0.z + a1.z + a2.z + a3.z + hv.z);
    float ow = dv * (a0.w + a1.w + a2.w + a3.w + hv.w);
    ushort4 ob;
    ob.x = f2bf(ox); ob.y = f2bf(oy); ob.z = f2bf(oz); ob.w = f2bf(ow);
    ((ushort4*)outp)[(size_t)v * 64 + lane] = ob;
}

// ---------------------------------------------------------------- mean pool (1024 thr/block: 4 node-subsets)
__global__ __launch_bounds__(1024) void k_pool(const unsigned short* __restrict__ h2b,
                                               const int* __restrict__ batch,
                                               float* __restrict__ hg) {
    int g = blockIdx.x;
    int tid = threadIdx.x;
    int sub = tid >> 8;        // 0..3: node-subset
    int feat = tid & 255;
    __shared__ float part[4][F_H];
    __shared__ int sBeg, sEnd;
    if (tid == 0) {
        int lo = 0, hi = N_NODES;
        while (lo < hi) { int mid = (lo + hi) >> 1; if (batch[mid] < g) lo = mid + 1; else hi = mid; }
        sBeg = lo;
        hi = N_NODES;
        while (lo < hi) { int mid = (lo + hi) >> 1; if (batch[mid] < g + 1) lo = mid + 1; else hi = mid; }
        sEnd = lo;
    }
    __syncthreads();
    int beg = sBeg, end = sEnd;
    float acc = 0.0f;
    #pragma unroll 4
    for (int v = beg + sub; v < end; v += 4)
        acc += bf2f(h2b[(size_t)v * F_H + feat]);
    part[sub][feat] = acc;
    __syncthreads();
    if (tid < F_H) {
        float s = part[0][tid] + part[1][tid] + part[2][tid] + part[3][tid];
        hg[(size_t)g * F_H + tid] = s / fmaxf((float)(end - beg), 1.0f);
    }
}

// ---------------------------------------------------------------- fused head + dec1 + dec2
// One block per graph; mu/logvar computed split-K across 256 threads.
__global__ __launch_bounds__(256) void k_head_dec(const float* __restrict__ hg,
                                                  const float* __restrict__ Wmu,
                                                  const float* __restrict__ bmu,
                                                  const float* __restrict__ Wlv,
                                                  const float* __restrict__ blv,
                                                  const float* __restrict__ eps,
                                                  const float* __restrict__ D1,
                                                  const float* __restrict__ db1,
                                                  const float* __restrict__ D2,
                                                  const float* __restrict__ db2,
                                                  float* __restrict__ out,
                                                  unsigned short* __restrict__ d2b) {
    int g = blockIdx.x;
    int tid = threadIdx.x;
    __shared__ float hgs[F_H];
    __shared__ float pp[256];
    __shared__ float mulv[128];
    __shared__ float zs[F_L];
    __shared__ float d1s[F_H];
    hgs[tid] = hg[(size_t)g * F_H + tid];
    __syncthreads();
    {   // mu/lv: 128 outputs x 2 K-halves
        int o    = tid & 127;          // 0..63 mu, 64..127 lv
        int half = tid >> 7;           // K half
        int l = o & 63;
        const float* W = (o < 64) ? Wmu : Wlv;
        float s = 0.0f;
        int k0 = half * 128;
        #pragma unroll 8
        for (int k = k0; k < k0 + 128; ++k) s += hgs[k] * W[(size_t)k * F_L + l];
        pp[tid] = s;
    }
    __syncthreads();
    if (tid < 128) {
        int l = tid & 63;
        float s = pp[tid] + pp[tid + 128] + ((tid < 64) ? bmu[l] : blv[l]);
        out[((tid < 64) ? MU_OFF : LV_OFF) + g * F_L + l] = s;
        mulv[tid] = s;
    }
    __syncthreads();
    if (tid < 64)
        zs[tid] = mulv[tid] + eps[g * F_L + tid] * expf(0.5f * mulv[64 + tid]);
    __syncthreads();
    {   // d1 = relu(z @ D1 + db1): K=64
        float s = db1[tid];
        #pragma unroll 8
        for (int k = 0; k < F_L; ++k) s += zs[k] * D1[(size_t)k * F_H + tid];
        d1s[tid] = fmaxf(s, 0.0f);
    }
    __syncthreads();
    {   // d2 = relu(d1 @ D2 + db2): K=256
        float s = db2[tid];
        #pragma unroll 8
        for (int k = 0; k < F_H; ++k) s += d1s[k] * D2[(size_t)k * F_H + tid];
        d2b[(size_t)g * F_H + tid] = f2bf(fmaxf(s, 0.0f));
    }
}

// ---------------------------------------------------------------- adjacency expansion
__global__ __launch_bounds__(256) void k_adj(const float* __restrict__ probs,
                                             float* __restrict__ adj) {
    int i = blockIdx.x * blockDim.x + threadIdx.x;
    if (i >= ADJ_SIZE) return;
    int g = i / (MAXN * MAXN);
    int r = i % (MAXN * MAXN);
    int a = r / MAXN, b = r % MAXN;
    float v = 0.0f;
    if (a != b) {
        int lo = min(a, b), hi = max(a, b);
        int p = lo * (MAXN - 1) - (lo * (lo - 1)) / 2 + (hi - lo - 1);
        v = probs[(size_t)g * P_PAIRS + p];
    }
    adj[i] = v;
}

// ================================================================ launch
extern "C" void kernel_launch(void* const* d_in, const int* in_sizes, int n_in,
                              void* d_out, int out_size, void* d_ws, size_t ws_size,
                              hipStream_t stream) {
    const float* x    = (const float*)d_in[0];
    const int*   eidx = (const int*)d_in[1];
    const int*   batch= (const int*)d_in[2];
    const float* eps  = (const float*)d_in[3];
    const float* W1   = (const float*)d_in[4];
    const float* b1   = (const float*)d_in[5];
    const float* W2   = (const float*)d_in[6];
    const float* b2   = (const float*)d_in[7];
    const float* Wmu  = (const float*)d_in[8];
    const float* bmu  = (const float*)d_in[9];
    const float* Wlv  = (const float*)d_in[10];
    const float* blv  = (const float*)d_in[11];
    const float* D1   = (const float*)d_in[12];
    const float* db1  = (const float*)d_in[13];
    const float* D2   = (const float*)d_in[14];
    const float* db2  = (const float*)d_in[15];
    const float* D3   = (const float*)d_in[16];
    const float* db3  = (const float*)d_in[17];

    const int* src = eidx;
    const int* dst = eidx + N_EDGES;
    float* out = (float*)d_out;

    // workspace carve-up
    char* wsb = (char*)d_ws;
    size_t o = 0;
    auto carve = [&](size_t bytes) { void* p = wsb + o; o += (bytes + 255) & ~255ull; return p; };
    int*   deg    = (int*)  carve(N_NODES * sizeof(int));   // contiguous with fill
    int*   fill   = (int*)  carve(N_NODES * sizeof(int));
    int*   rowptr = (int*)  carve((N_NODES + 1) * sizeof(int));
    int*   bsum   = (int*)  carve(128 * sizeof(int));
    int*   col    = (int*)  carve(N_EDGES * sizeof(int));
    float* dinv   = (float*)carve(N_NODES * sizeof(float));
    unsigned short* xs  = (unsigned short*)carve((size_t)N_NODES * F_IN * sizeof(short));
    unsigned short* W1p = (unsigned short*)carve((size_t)F_IN * F_H * sizeof(short));
    unsigned short* W2p = (unsigned short*)carve((size_t)F_H * F_H * sizeof(short));
    unsigned short* D3p = (unsigned short*)carve((size_t)F_H * P_PAD * sizeof(short));
    unsigned short* g1  = (unsigned short*)carve((size_t)N_NODES * F_IN * sizeof(short)); // agg x
    unsigned short* h1s = (unsigned short*)carve((size_t)N_NODES * F_H * sizeof(short));  // dinv*h1
    unsigned short* g2  = (unsigned short*)carve((size_t)N_NODES * F_H * sizeof(short));  // agg h1
    unsigned short* h2b = (unsigned short*)carve((size_t)N_NODES * F_H * sizeof(short));  // h2
    float* hg     = (float*)carve((size_t)N_GRAPHS * F_H * sizeof(float));
    unsigned short* d2b = (unsigned short*)carve((size_t)N_GRAPHS * F_H * sizeof(short));
    float* probs  = (float*)carve((size_t)N_GRAPHS * P_PAIRS * sizeof(float));

    // ---- CSR build (deg+fill zeroed in one contiguous memset)
    hipMemsetAsync(deg, 0, 160256, stream);
    k_deg<<<ceil_div(N_EDGES, 256), 256, 0, stream>>>(dst, deg, N_EDGES);
    k_scan_local<<<SCAN_NB, 256, 0, stream>>>(deg, rowptr, bsum, dinv, N_NODES);
    k_scan_add<<<SCAN_NB, 256, 0, stream>>>(rowptr, bsum, N_NODES);
    k_fill<<<ceil_div(N_EDGES, 256), 256, 0, stream>>>(src, dst, rowptr, fill, col, N_EDGES);

    // ---- fused xs-cast (dinv-scaled) + weight prepack
    k_cvt_prepack<<<ceil_div(CV_END + PP_END, 256), 256, 0, stream>>>(
        x, dinv, xs, W1, W2, D3, W1p, W2p, D3p);

    // ---- GCN layer 1: aggregate x first (128 feats), then MFMA transform
    k_gather1<<<ceil_div(N_NODES, 4), 256, 0, stream>>>(xs, rowptr, col, dinv, g1);
    {
        dim3 grid(F_H / 64, ceil_div(N_NODES, 128));
        k_gemm<F_IN, 2><<<grid, 256, 0, stream>>>(g1, W1p, h1s, b1, dinv, N_NODES, F_H, F_H);
    }

    // ---- GCN layer 2: aggregate h1s (256 feats), then MFMA transform
    k_gather2<<<ceil_div(N_NODES, 4), 256, 0, stream>>>(h1s, rowptr, col, dinv, g2);
    {
        dim3 grid(F_H / 64, ceil_div(N_NODES, 128));
        k_gemm<F_H, 1><<<grid, 256, 0, stream>>>(g2, W2p, h2b, b2, nullptr, N_NODES, F_H, F_H);
    }

    // ---- mean pool (parallel over 4 node-subsets) + head/dec1/dec2
    k_pool<<<N_GRAPHS, 1024, 0, stream>>>(h2b, batch, hg);
    k_head_dec<<<N_GRAPHS, 256, 0, stream>>>(hg, Wmu, bmu, Wlv, blv, eps,
                                             D1, db1, D2, db2, out, d2b);

    // ---- decoder D3 (MFMA, sigmoid)
    {
        dim3 grid(P_PAD / 64, ceil_div(N_GRAPHS, 128));
        k_gemm<F_H, 3><<<grid, 256, 0, stream>>>(d2b, D3p, probs, db3, nullptr,
                                                 N_GRAPHS, P_PAIRS, P_PAD);
    }

    // ---- adjacency expansion
    k_adj<<<ceil_div(ADJ_SIZE, 256), 256, 0, stream>>>(probs, out);
}

// Round 10
// 268.211 us; speedup vs baseline: 1.0307x; 1.0307x over previous
//
#include <hip/hip_runtime.h>
#include <math.h>

#define N_NODES  20000
#define N_EDGES  320000
#define N_GRAPHS 200
#define MAXN     100
#define F_IN     128
#define F_H      256
#define F_L      64
#define P_PAIRS  4950
#define P_PAD    4992                       // P_PAIRS padded to multiple of 64
#define ADJ_SIZE (N_GRAPHS * MAXN * MAXN)   // 2,000,000
#define MU_OFF   ADJ_SIZE
#define LV_OFF   (ADJ_SIZE + N_GRAPHS * F_L)

#define SCAN_NB  ((N_NODES + 255) / 256)    // 79 blocks
#define DEG_NB   ((N_EDGES + 255) / 256)    // 1250 blocks

static inline int ceil_div(int a, int b) { return (a + b - 1) / b; }

typedef __attribute__((ext_vector_type(8))) short bf16x8;   // 4 VGPRs
typedef __attribute__((ext_vector_type(4))) float f32x4;    // MFMA acc

// fp32 -> bf16 round-to-nearest-even
static __device__ inline unsigned short f2bf(float f) {
    union { float f; unsigned u; } v; v.f = f;
    unsigned r = (v.u + 0x7FFFu + ((v.u >> 16) & 1u)) >> 16;
    return (unsigned short)r;
}
static __device__ inline float bf2f(unsigned short s) {
    union { unsigned u; float f; } v; v.u = (unsigned)s << 16; return v.f;
}
static __device__ inline float4 ubf4(ushort4 u) {
    float4 f;
    f.x = bf2f(u.x); f.y = bf2f(u.y); f.z = bf2f(u.z); f.w = bf2f(u.w);
    return f;
}

// ---------------------------------------------------------------- fused degree histogram + weight prepack
// Blocks [0, DEG_NB): degree atomics. Blocks [DEG_NB, ...): prepack W1/W2/D3 into
// B-fragment order: Bp[((kt*NT+nt)*64+lane)*8+j] = bf16(W[kt*32+(lane>>4)*8+j][nt*16+(lane&15)])
#define PP_S1  32768                       // W1: 128*256
#define PP_S2  98304                       // + W2: 256*256
#define PP_END 1376256                     // + D3: 256*4992
#define PP_NB  (PP_END / 256)              // 5376
__global__ __launch_bounds__(256) void k_deg_prepack(
        const int* __restrict__ dst, int* __restrict__ deg,
        const float* __restrict__ W1, const float* __restrict__ W2,
        const float* __restrict__ D3,
        unsigned short* __restrict__ W1p, unsigned short* __restrict__ W2p,
        unsigned short* __restrict__ D3p) {
    if (blockIdx.x < DEG_NB) {
        int i = blockIdx.x * 256 + threadIdx.x;
        if (i < N_EDGES) atomicAdd(deg + dst[i], 1);
        return;
    }
    int pid = (blockIdx.x - DEG_NB) * 256 + threadIdx.x;
    const float* W; unsigned short* Bp; int N, NP, t;
    if (pid < PP_S1)      { t = pid;          W = W1; Bp = W1p; N = 256;     NP = 256; }
    else if (pid < PP_S2) { t = pid - PP_S1;  W = W2; Bp = W2p; N = 256;     NP = 256; }
    else if (pid < PP_END){ t = pid - PP_S2;  W = D3; Bp = D3p; N = P_PAIRS; NP = P_PAD; }
    else return;
    int j    = t & 7;
    int lane = (t >> 3) & 63;
    int tile = t >> 9;
    int NT = NP >> 4;
    int nt = tile % NT;
    int kt = tile / NT;
    int k = kt * 32 + (lane >> 4) * 8 + j;
    int n = nt * 16 + (lane & 15);
    Bp[t] = (n < N) ? f2bf(W[(size_t)k * N + n]) : (unsigned short)0;
}

// ---------------------------------------------------------------- scan phase A (+dinv fused)
__global__ __launch_bounds__(256) void k_scan_local(const int* __restrict__ deg,
                                                    int* __restrict__ rowptr,
                                                    int* __restrict__ bsum,
                                                    float* __restrict__ dinv, int n) {
    __shared__ int tmp[256];
    int i = blockIdx.x * 256 + threadIdx.x;
    int v = (i < n) ? deg[i] : 0;
    if (i < n) dinv[i] = rsqrtf((float)v + 1.0f);   // +1 self-loop
    tmp[threadIdx.x] = v;
    __syncthreads();
    #pragma unroll
    for (int off = 1; off < 256; off <<= 1) {
        int t = (threadIdx.x >= (unsigned)off) ? tmp[threadIdx.x - off] : 0;
        __syncthreads();
        tmp[threadIdx.x] += t;
        __syncthreads();
    }
    if (i < n) rowptr[i + 1] = tmp[threadIdx.x];
    if (threadIdx.x == 255) bsum[blockIdx.x] = tmp[255];
}

// ---------------------------------------------------------------- scan phase B (+xs-cast fused)
// Blocks [0, SCAN_NB): add block offsets. Blocks [SCAN_NB, ...): xs = bf16(dinv*x).
#define CV_END 640000                      // N_NODES*F_IN/4 float4 elements
#define CV_NB  (CV_END / 256)              // 2500
__global__ __launch_bounds__(256) void k_scanadd_xs(int* __restrict__ rowptr,
                                                    const int* __restrict__ bsum, int n,
                                                    const float* __restrict__ x,
                                                    const float* __restrict__ dinv,
                                                    unsigned short* __restrict__ xs) {
    if (blockIdx.x < SCAN_NB) {
        __shared__ int red[256];
        int t = threadIdx.x;
        red[t] = (t < (int)blockIdx.x) ? bsum[t] : 0;   // SCAN_NB (79) < 256
        __syncthreads();
        #pragma unroll
        for (int off = 128; off > 0; off >>= 1) {
            if (t < off) red[t] += red[t + off];
            __syncthreads();
        }
        int offv = red[0];
        int i = blockIdx.x * 256 + t;
        if (i < n) rowptr[i + 1] += offv;
        if (blockIdx.x == 0 && t == 0) rowptr[0] = 0;
        return;
    }
    int tid = (blockIdx.x - SCAN_NB) * 256 + threadIdx.x;
    if (tid >= CV_END) return;
    int v = tid >> 5;                  // 32 float4 per row of 128
    float dv = dinv[v];
    float4 val = ((const float4*)x)[tid];
    ushort4 o;
    o.x = f2bf(val.x * dv); o.y = f2bf(val.y * dv);
    o.z = f2bf(val.z * dv); o.w = f2bf(val.w * dv);
    ((ushort4*)xs)[tid] = o;
}

// ---------------------------------------------------------------- CSR fill
__global__ __launch_bounds__(256) void k_fill(const int* __restrict__ src,
                                              const int* __restrict__ dst,
                                              const int* __restrict__ rowptr,
                                              int* __restrict__ fill,
                                              int* __restrict__ col, int nE) {
    int e = blockIdx.x * blockDim.x + threadIdx.x;
    if (e >= nE) return;
    int d = dst[e];
    int pos = rowptr[d] + atomicAdd(fill + d, 1);
    col[pos] = src[e];
}

// ---------------------------------------------------------------- unified MFMA bf16 GEMM
// Y = epi(A[M,K]bf16 @ Bp + bias); LDS-free, barrier-free; wave tile 32x64, block 128x64.
// MODE 1: relu -> bf16           (layer-2: h2)
// MODE 2: relu * dinv[m] -> bf16 (layer-1: h1s, pre-scaled for gather)
// MODE 3: sigmoid -> fp32        (decoder D3)
template<int KDIM, int MODE>
__global__ __launch_bounds__(256) void k_gemm(const unsigned short* __restrict__ A,
                                              const unsigned short* __restrict__ Bp,
                                              void* __restrict__ Y,
                                              const float* __restrict__ bias,
                                              const float* __restrict__ dinv,
                                              int M, int N, int NP) {
    constexpr int KT = KDIM / 32;
    const int NT   = NP >> 4;
    const int lane = threadIdx.x & 63;
    const int wave = threadIdx.x >> 6;
    const int bm   = blockIdx.y * 128 + wave * 32;
    const int ng0  = blockIdx.x * 4;
    const int quad = lane >> 4;
    const int l15  = lane & 15;

    int m0 = bm + l15;
    int m1 = m0 + 16;
    int m0c = min(m0, M - 1), m1c = min(m1, M - 1);

    f32x4 acc[2][4];
    #pragma unroll
    for (int i = 0; i < 2; ++i)
        #pragma unroll
        for (int nt = 0; nt < 4; ++nt) acc[i][nt] = (f32x4){0.f, 0.f, 0.f, 0.f};

    #pragma unroll
    for (int kt = 0; kt < KT; ++kt) {
        bf16x8 a0 = *(const bf16x8*)(A + (size_t)m0c * KDIM + kt * 32 + quad * 8);
        bf16x8 a1 = *(const bf16x8*)(A + (size_t)m1c * KDIM + kt * 32 + quad * 8);
        #pragma unroll
        for (int nt = 0; nt < 4; ++nt) {
            bf16x8 b = *(const bf16x8*)(Bp + (((size_t)kt * NT + ng0 + nt) * 64 + lane) * 8);
            acc[0][nt] = __builtin_amdgcn_mfma_f32_16x16x32_bf16(a0, b, acc[0][nt], 0, 0, 0);
            acc[1][nt] = __builtin_amdgcn_mfma_f32_16x16x32_bf16(a1, b, acc[1][nt], 0, 0, 0);
        }
    }

    // C/D layout: col = lane&15, row = quad*4 + reg
    #pragma unroll
    for (int i = 0; i < 2; ++i) {
        #pragma unroll
        for (int r = 0; r < 4; ++r) {
            int gm = bm + i * 16 + quad * 4 + r;
            if (gm >= M) continue;
            float dv = (MODE == 2) ? dinv[gm] : 1.0f;
            #pragma unroll
            for (int nt = 0; nt < 4; ++nt) {
                int gn = ((ng0 + nt) << 4) + l15;
                if (gn >= N) continue;
                float s = acc[i][nt][r] + bias[gn];
                if constexpr (MODE == 1) {
                    ((unsigned short*)Y)[(size_t)gm * N + gn] = f2bf(fmaxf(s, 0.0f));
                } else if constexpr (MODE == 2) {
                    ((unsigned short*)Y)[(size_t)gm * N + gn] = f2bf(fmaxf(s, 0.0f) * dv);
                } else {
                    ((float*)Y)[(size_t)gm * N + gn] = 1.0f / (1.0f + expf(-s));
                }
            }
        }
    }
}

// ---------------------------------------------------------------- gather layer 1 (128 feats)
// 512 threads = 8 waves; 2 waves per node (edge-list halves), LDS combine.
__global__ __launch_bounds__(512) void k_gather1(const unsigned short* __restrict__ xs,
                                                 const int* __restrict__ rowptr,
                                                 const int* __restrict__ col,
                                                 const float* __restrict__ dinv,
                                                 unsigned short* __restrict__ outp) {
    __shared__ float2 part[4][64];
    int w = threadIdx.x >> 6;
    int nl = w >> 1;                 // node slot 0..3
    int half = w & 1;
    int v = blockIdx.x * 4 + nl;     // grid exact: 20000/4
    int lane = threadIdx.x & 63;
    int beg = rowptr[v], end = rowptr[v + 1];
    int mid = beg + ((end - beg) >> 1);
    int lo = half ? mid : beg;
    int hi = half ? end : mid;
    float2 a0 = make_float2(0.f, 0.f), a1 = make_float2(0.f, 0.f);
    int i = lo;
    for (; i + 4 <= hi; i += 4) {
        int s0 = col[i + 0], s1 = col[i + 1], s2 = col[i + 2], s3 = col[i + 3];
        ushort2 u0 = ((const ushort2*)(xs + (size_t)s0 * F_IN))[lane];
        ushort2 u1 = ((const ushort2*)(xs + (size_t)s1 * F_IN))[lane];
        ushort2 u2 = ((const ushort2*)(xs + (size_t)s2 * F_IN))[lane];
        ushort2 u3 = ((const ushort2*)(xs + (size_t)s3 * F_IN))[lane];
        a0.x += bf2f(u0.x) + bf2f(u2.x); a0.y += bf2f(u0.y) + bf2f(u2.y);
        a1.x += bf2f(u1.x) + bf2f(u3.x); a1.y += bf2f(u1.y) + bf2f(u3.y);
    }
    for (; i < hi; ++i) {
        int s = col[i];
        ushort2 u = ((const ushort2*)(xs + (size_t)s * F_IN))[lane];
        a0.x += bf2f(u.x); a0.y += bf2f(u.y);
    }
    if (half) part[nl][lane] = make_float2(a0.x + a1.x, a0.y + a1.y);
    __syncthreads();
    if (!half) {
        float2 p = part[nl][lane];
        float dv = dinv[v];
        ushort2 uv = ((const ushort2*)(xs + (size_t)v * F_IN))[lane];
        float ox = dv * (a0.x + a1.x + p.x + bf2f(uv.x));
        float oy = dv * (a0.y + a1.y + p.y + bf2f(uv.y));
        ushort2 ob; ob.x = f2bf(ox); ob.y = f2bf(oy);
        ((ushort2*)outp)[(size_t)v * 64 + lane] = ob;
    }
}

// ---------------------------------------------------------------- gather layer 2 (256 feats)
// 512 threads = 8 waves; 2 waves per node (edge-list halves), LDS combine.
__global__ __launch_bounds__(512) void k_gather2(const unsigned short* __restrict__ Hs,
                                                 const int* __restrict__ rowptr,
                                                 const int* __restrict__ col,
                                                 const float* __restrict__ dinv,
                                                 unsigned short* __restrict__ outp) {
    __shared__ float4 part[4][64];
    int w = threadIdx.x >> 6;
    int nl = w >> 1;
    int half = w & 1;
    int v = blockIdx.x * 4 + nl;
    int lane = threadIdx.x & 63;
    int beg = rowptr[v], end = rowptr[v + 1];
    int mid = beg + ((end - beg) >> 1);
    int lo = half ? mid : beg;
    int hi = half ? end : mid;
    float4 a0 = make_float4(0.f, 0.f, 0.f, 0.f);
    float4 a1 = make_float4(0.f, 0.f, 0.f, 0.f);
    int i = lo;
    for (; i + 4 <= hi; i += 4) {
        int s0 = col[i + 0], s1 = col[i + 1], s2 = col[i + 2], s3 = col[i + 3];
        float4 h0 = ubf4(((const ushort4*)(Hs + (size_t)s0 * F_H))[lane]);
        float4 h1 = ubf4(((const ushort4*)(Hs + (size_t)s1 * F_H))[lane]);
        float4 h2 = ubf4(((const ushort4*)(Hs + (size_t)s2 * F_H))[lane]);
        float4 h3 = ubf4(((const ushort4*)(Hs + (size_t)s3 * F_H))[lane]);
        a0.x += h0.x + h2.x; a0.y += h0.y + h2.y; a0.z += h0.z + h2.z; a0.w += h0.w + h2.w;
        a1.x += h1.x + h3.x; a1.y += h1.y + h3.y; a1.z += h1.z + h3.z; a1.w += h1.w + h3.w;
    }
    for (; i < hi; ++i) {
        int s = col[i];
        float4 h = ubf4(((const ushort4*)(Hs + (size_t)s * F_H))[lane]);
        a0.x += h.x; a0.y += h.y; a0.z += h.z; a0.w += h.w;
    }
    if (half) part[nl][lane] = make_float4(a0.x + a1.x, a0.y + a1.y,
                                           a0.z + a1.z, a0.w + a1.w);
    __syncthreads();
    if (!half) {
        float4 p = part[nl][lane];
        float dv = dinv[v];
        float4 hv = ubf4(((const ushort4*)(Hs + (size_t)v * F_H))[lane]);
        float ox = dv * (a0.x + a1.x + p.x + hv.x);
        float oy = dv * (a0.y + a1.y + p.y + hv.y);
        float oz = dv * (a0.z + a1.z + p.z + hv.z);
        float ow = dv * (a0.w + a1.w + p.w + hv.w);
        ushort4 ob;
        ob.x = f2bf(ox); ob.y = f2bf(oy); ob.z = f2bf(oz); ob.w = f2bf(ow);
        ((ushort4*)outp)[(size_t)v * 64 + lane] = ob;
    }
}

// ---------------------------------------------------------------- mean pool
// Grid (N_GRAPHS, 2): block covers 128 feats; 1024 thr = 8 node-subsets x 128 feats.
__global__ __launch_bounds__(1024) void k_pool(const unsigned short* __restrict__ h2b,
                                               const int* __restrict__ batch,
                                               float* __restrict__ hg) {
    int g = blockIdx.x;
    int fb = blockIdx.y * 128;
    int tid = threadIdx.x;
    int sub = tid >> 7;        // 0..7
    int feat = tid & 127;
    __shared__ float part[8][128];
    __shared__ int sBeg, sEnd;
    if (tid == 0) {
        int lo = 0, hi = N_NODES;
        while (lo < hi) { int mid = (lo + hi) >> 1; if (batch[mid] < g) lo = mid + 1; else hi = mid; }
        sBeg = lo;
        hi = N_NODES;
        while (lo < hi) { int mid = (lo + hi) >> 1; if (batch[mid] < g + 1) lo = mid + 1; else hi = mid; }
        sEnd = lo;
    }
    __syncthreads();
    int beg = sBeg, end = sEnd;
    float acc = 0.0f;
    #pragma unroll 4
    for (int v = beg + sub; v < end; v += 8)
        acc += bf2f(h2b[(size_t)v * F_H + fb + feat]);
    part[sub][feat] = acc;
    __syncthreads();
    if (tid < 128) {
        float s = part[0][tid] + part[1][tid] + part[2][tid] + part[3][tid]
                + part[4][tid] + part[5][tid] + part[6][tid] + part[7][tid];
        hg[(size_t)g * F_H + fb + tid] = s / fmaxf((float)(end - beg), 1.0f);
    }
}

// ---------------------------------------------------------------- fused head + dec1 + dec2
__global__ __launch_bounds__(256) void k_head_dec(const float* __restrict__ hg,
                                                  const float* __restrict__ Wmu,
                                                  const float* __restrict__ bmu,
                                                  const float* __restrict__ Wlv,
                                                  const float* __restrict__ blv,
                                                  const float* __restrict__ eps,
                                                  const float* __restrict__ D1,
                                                  const float* __restrict__ db1,
                                                  const float* __restrict__ D2,
                                                  const float* __restrict__ db2,
                                                  float* __restrict__ out,
                                                  unsigned short* __restrict__ d2b) {
    int g = blockIdx.x;
    int tid = threadIdx.x;
    __shared__ float hgs[F_H];
    __shared__ float pp[256];
    __shared__ float mulv[128];
    __shared__ float zs[F_L];
    __shared__ float d1s[F_H];
    hgs[tid] = hg[(size_t)g * F_H + tid];
    __syncthreads();
    {   // mu/lv: 128 outputs x 2 K-halves
        int o    = tid & 127;          // 0..63 mu, 64..127 lv
        int half = tid >> 7;           // K half
        int l = o & 63;
        const float* W = (o < 64) ? Wmu : Wlv;
        float s = 0.0f;
        int k0 = half * 128;
        #pragma unroll 8
        for (int k = k0; k < k0 + 128; ++k) s += hgs[k] * W[(size_t)k * F_L + l];
        pp[tid] = s;
    }
    __syncthreads();
    if (tid < 128) {
        int l = tid & 63;
        float s = pp[tid] + pp[tid + 128] + ((tid < 64) ? bmu[l] : blv[l]);
        out[((tid < 64) ? MU_OFF : LV_OFF) + g * F_L + l] = s;
        mulv[tid] = s;
    }
    __syncthreads();
    if (tid < 64)
        zs[tid] = mulv[tid] + eps[g * F_L + tid] * expf(0.5f * mulv[64 + tid]);
    __syncthreads();
    {   // d1 = relu(z @ D1 + db1): K=64
        float s = db1[tid];
        #pragma unroll 8
        for (int k = 0; k < F_L; ++k) s += zs[k] * D1[(size_t)k * F_H + tid];
        d1s[tid] = fmaxf(s, 0.0f);
    }
    __syncthreads();
    {   // d2 = relu(d1 @ D2 + db2): K=256
        float s = db2[tid];
        #pragma unroll 8
        for (int k = 0; k < F_H; ++k) s += d1s[k] * D2[(size_t)k * F_H + tid];
        d2b[(size_t)g * F_H + tid] = f2bf(fmaxf(s, 0.0f));
    }
}

// ---------------------------------------------------------------- adjacency expansion (float4 stores)
__global__ __launch_bounds__(256) void k_adj(const float* __restrict__ probs,
                                             float* __restrict__ adj) {
    int i = blockIdx.x * blockDim.x + threadIdx.x;   // (g, a, b4): 200*100*25
    if (i >= N_GRAPHS * MAXN * (MAXN / 4)) return;
    int b4 = (i % (MAXN / 4)) * 4;
    int a  = (i / (MAXN / 4)) % MAXN;
    int g  = i / (MAXN * (MAXN / 4));
    const float* pg = probs + (size_t)g * P_PAIRS;
    float4 o;
    float* op = (float*)&o;
    #pragma unroll
    for (int c = 0; c < 4; ++c) {
        int b = b4 + c;
        float v = 0.0f;
        if (a != b) {
            int lo = min(a, b), hi = max(a, b);
            int p = lo * (MAXN - 1) - (lo * (lo - 1)) / 2 + (hi - lo - 1);
            v = pg[p];
        }
        op[c] = v;
    }
    ((float4*)adj)[i] = o;
}

// ================================================================ launch
extern "C" void kernel_launch(void* const* d_in, const int* in_sizes, int n_in,
                              void* d_out, int out_size, void* d_ws, size_t ws_size,
                              hipStream_t stream) {
    const float* x    = (const float*)d_in[0];
    const int*   eidx = (const int*)d_in[1];
    const int*   batch= (const int*)d_in[2];
    const float* eps  = (const float*)d_in[3];
    const float* W1   = (const float*)d_in[4];
    const float* b1   = (const float*)d_in[5];
    const float* W2   = (const float*)d_in[6];
    const float* b2   = (const float*)d_in[7];
    const float* Wmu  = (const float*)d_in[8];
    const float* bmu  = (const float*)d_in[9];
    const float* Wlv  = (const float*)d_in[10];
    const float* blv  = (const float*)d_in[11];
    const float* D1   = (const float*)d_in[12];
    const float* db1  = (const float*)d_in[13];
    const float* D2   = (const float*)d_in[14];
    const float* db2  = (const float*)d_in[15];
    const float* D3   = (const float*)d_in[16];
    const float* db3  = (const float*)d_in[17];

    const int* src = eidx;
    const int* dst = eidx + N_EDGES;
    float* out = (float*)d_out;

    // workspace carve-up
    char* wsb = (char*)d_ws;
    size_t o = 0;
    auto carve = [&](size_t bytes) { void* p = wsb + o; o += (bytes + 255) & ~255ull; return p; };
    int*   deg    = (int*)  carve(N_NODES * sizeof(int));   // contiguous with fill
    int*   fill   = (int*)  carve(N_NODES * sizeof(int));
    int*   rowptr = (int*)  carve((N_NODES + 1) * sizeof(int));
    int*   bsum   = (int*)  carve(128 * sizeof(int));
    int*   col    = (int*)  carve(N_EDGES * sizeof(int));
    float* dinv   = (float*)carve(N_NODES * sizeof(float));
    unsigned short* xs  = (unsigned short*)carve((size_t)N_NODES * F_IN * sizeof(short));
    unsigned short* W1p = (unsigned short*)carve((size_t)F_IN * F_H * sizeof(short));
    unsigned short* W2p = (unsigned short*)carve((size_t)F_H * F_H * sizeof(short));
    unsigned short* D3p = (unsigned short*)carve((size_t)F_H * P_PAD * sizeof(short));
    unsigned short* g1  = (unsigned short*)carve((size_t)N_NODES * F_IN * sizeof(short)); // agg x
    unsigned short* h1s = (unsigned short*)carve((size_t)N_NODES * F_H * sizeof(short));  // dinv*h1
    unsigned short* g2  = (unsigned short*)carve((size_t)N_NODES * F_H * sizeof(short));  // agg h1
    unsigned short* h2b = (unsigned short*)carve((size_t)N_NODES * F_H * sizeof(short));  // h2
    float* hg     = (float*)carve((size_t)N_GRAPHS * F_H * sizeof(float));
    unsigned short* d2b = (unsigned short*)carve((size_t)N_GRAPHS * F_H * sizeof(short));
    float* probs  = (float*)carve((size_t)N_GRAPHS * P_PAIRS * sizeof(float));

    // ---- CSR build + prepack (deg+fill zeroed in one contiguous memset)
    hipMemsetAsync(deg, 0, 160256, stream);
    k_deg_prepack<<<DEG_NB + PP_NB, 256, 0, stream>>>(dst, deg, W1, W2, D3,
                                                      W1p, W2p, D3p);
    k_scan_local<<<SCAN_NB, 256, 0, stream>>>(deg, rowptr, bsum, dinv, N_NODES);
    k_scanadd_xs<<<SCAN_NB + CV_NB, 256, 0, stream>>>(rowptr, bsum, N_NODES, x, dinv, xs);
    k_fill<<<ceil_div(N_EDGES, 256), 256, 0, stream>>>(src, dst, rowptr, fill, col, N_EDGES);

    // ---- GCN layer 1: aggregate x first (128 feats), then MFMA transform
    k_gather1<<<N_NODES / 4, 512, 0, stream>>>(xs, rowptr, col, dinv, g1);
    {
        dim3 grid(F_H / 64, ceil_div(N_NODES, 128));
        k_gemm<F_IN, 2><<<grid, 256, 0, stream>>>(g1, W1p, h1s, b1, dinv, N_NODES, F_H, F_H);
    }

    // ---- GCN layer 2: aggregate h1s (256 feats), then MFMA transform
    k_gather2<<<N_NODES / 4, 512, 0, stream>>>(h1s, rowptr, col, dinv, g2);
    {
        dim3 grid(F_H / 64, ceil_div(N_NODES, 128));
        k_gemm<F_H, 1><<<grid, 256, 0, stream>>>(g2, W2p, h2b, b2, nullptr, N_NODES, F_H, F_H);
    }

    // ---- mean pool (8-way node split, per-feat-half blocks) + head/dec1/dec2
    {
        dim3 pgrid(N_GRAPHS, 2);
        k_pool<<<pgrid, 1024, 0, stream>>>(h2b, batch, hg);
    }
    k_head_dec<<<N_GRAPHS, 256, 0, stream>>>(hg, Wmu, bmu, Wlv, blv, eps,
                                             D1, db1, D2, db2, out, d2b);

    // ---- decoder D3 (MFMA, sigmoid)
    {
        dim3 grid(P_PAD / 64, ceil_div(N_GRAPHS, 128));
        k_gemm<F_H, 3><<<grid, 256, 0, stream>>>(d2b, D3p, probs, db3, nullptr,
                                                 N_GRAPHS, P_PAIRS, P_PAD);
    }

    // ---- adjacency expansion (vec4)
    k_adj<<<ceil_div(N_GRAPHS * MAXN * (MAXN / 4), 256), 256, 0, stream>>>(probs, out);
}